// Round 16
// baseline (201.575 us; speedup 1.0000x reference)
//
#include <hip/hip_runtime.h>
#include <hip/hip_bf16.h>
#include <math.h>

#define B_ 2
#define T_ 2048
#define C_ 1024
#define H_ 16
#define G_ 4
#define DQK_ 64
#define DV_ 128
#define NQKV 1792   // H*DQK + G*DQK + G*DV
#define KS2 2048    // compact split storage: [hi | lo]
// Variable-K split GEMM: Q/K columns (n<1280) use 2048 K-depth
// (hi·hi + lo·hi); V columns (n>=1280) use 1024 (hi·hi only).
// Operand rows chunk-XOR-swizzled: chunk c of row r at phys chunk c^((r>>1)&3).

typedef __attribute__((ext_vector_type(8))) short short8;
typedef __attribute__((ext_vector_type(4))) float f32x4;
typedef unsigned short ushort_t;

__device__ inline ushort_t f2bf(float f) {
  union { float f; unsigned int u; } v; v.f = f;
  unsigned int r = (v.u + 0x7FFFu + ((v.u >> 16) & 1u)) >> 16;  // RNE
  return (ushort_t)r;
}
__device__ inline float bf2f(ushort_t h) {
  union { unsigned int u; float f; } v; v.u = ((unsigned int)h) << 16;
  return v.f;
}
// single-instruction RNE f32->bf16 (dst.lo = cvt(src)); P is finite in (0,1]
__device__ inline ushort_t f2bf_hw(float f) {
  unsigned int u;
  asm("v_cvt_pk_bf16_f32 %0, %1, %1" : "=v"(u) : "v"(f));
  return (ushort_t)u;
}

#define GLD_LDS16(g, l)                                              \
  __builtin_amdgcn_global_load_lds(                                  \
      (const __attribute__((address_space(1))) void*)(g),            \
      (__attribute__((address_space(3))) void*)(l), 16, 0, 0)

// ---------------------------------------------------------------------------
// Kernel 0 (FUSED): prep = cast_x | cast_w | cast_wp | y-zero by range.
// ---------------------------------------------------------------------------
__global__ __launch_bounds__(256) void prep(
    const float* __restrict__ x, const float* __restrict__ Wq,
    const float* __restrict__ Wk, const float* __restrict__ Wv,
    const float* __restrict__ Wproj, ushort_t* __restrict__ xb,
    ushort_t* __restrict__ wt, ushort_t* __restrict__ wpf,
    float* __restrict__ y) {
  __shared__ float tile[64][65];
  const int bid = blockIdx.x;
  const int tid = threadIdx.x;

  if (bid < 2048) {
    // ---- cast_x ----
    int idx = bid * 256 + tid;   // 524288
    int m = idx >> 7;
    int c8 = idx & 127;
    const float* src = &x[(size_t)m * 1024 + c8 * 8];
    float4 v0 = *(const float4*)&src[0];
    float4 v1 = *(const float4*)&src[4];
    float f[8] = {v0.x, v0.y, v0.z, v0.w, v1.x, v1.y, v1.z, v1.w};
    short8 hv, lv;
#pragma unroll
    for (int c = 0; c < 8; c++) {
      ushort_t h = f2bf(f[c]);
      hv[c] = (short)h;
      lv[c] = (short)f2bf(f[c] - bf2f(h));
    }
    int key = (m >> 1) & 3;
    int phys = (c8 & ~3) * 8 + ((c8 & 3) ^ key) * 8;
    ushort_t* row = xb + (size_t)m * KS2;
    *(short8*)&row[phys] = hv;
    *(short8*)&row[1024 + phys] = lv;
  } else if (bid < 2496) {
    // ---- cast_w ----
    const int wid = bid - 2048;          // 0..447 = 28 x 16
    const int n0 = (wid % 28) * 64;
    const int k0 = (wid / 28) * 64;

    const float* Wp; int ldw, noff;
    if (n0 < 1024)      { Wp = Wq; ldw = 1024; noff = n0; }
    else if (n0 < 1280) { Wp = Wk; ldw = 256;  noff = n0 - 1024; }
    else                { Wp = Wv; ldw = 512;  noff = n0 - 1280; }

#pragma unroll
    for (int it = 0; it < 4; it++) {
      int fi = it * 256 + tid;
      int kk = fi >> 4;
      int nc = (fi & 15) * 4;
      float4 v = *(const float4*)&Wp[(size_t)(k0 + kk) * ldw + noff + nc];
      tile[nc + 0][kk] = v.x; tile[nc + 1][kk] = v.y;
      tile[nc + 2][kk] = v.z; tile[nc + 3][kk] = v.w;
    }
    __syncthreads();
    int nn = tid >> 2, seg = tid & 3;
    int n = n0 + nn;
    int key = (n >> 1) & 3;
    ushort_t* row = wt + (size_t)n * KS2;
#pragma unroll
    for (int j = 0; j < 2; j++) {
      short8 hv;
#pragma unroll
      for (int u = 0; u < 8; u++)
        hv[u] = (short)f2bf(tile[nn][seg * 16 + j * 8 + u]);
      int c8 = (k0 >> 3) + seg * 2 + j;
      int phys = (c8 & ~3) * 8 + ((c8 & 3) ^ key) * 8;
      *(short8*)&row[phys] = hv;
    }
  } else if (bid < 2560) {
    // ---- cast_wp ----
    int idx = (bid - 2496) * 256 + tid;  // 16384
    int n = idx & 1023;
    int kc = idx >> 10;                  // 0..15 (chunk of 8 k's)
    short8 v;
#pragma unroll
    for (int j = 0; j < 8; j++)
      v[j] = (short)f2bf(Wproj[(size_t)(kc * 8 + j) * 1024 + n]);
    size_t off = (((size_t)(n >> 7) * 4 + (kc >> 2)) * 8 + ((n >> 4) & 7)) * 512 +
                 ((kc & 3) * 16 + (n & 15)) * 8;
    *(short8*)&wpf[off] = v;
  } else {
    // ---- zero y (y does not alias xb; safe to zero here) ----
    int idx = (bid - 2560) * 256 + tid;   // 131072 float4s
    *(float4*)&y[(size_t)idx * 4] = (float4){0.f, 0.f, 0.f, 0.f};
  }
}

// ---------------------------------------------------------------------------
// Kernel 1: bf16-MFMA QKV GEMM, BK=64, fully fused epilogue (r15 proven):
// V-cols -> vf PV-fragment store; Q/K-cols -> in-register RoPE + qk-norm +
// fragment store to qf/kf.  qkv f32 intermediate eliminated.
// ---------------------------------------------------------------------------
__global__ __launch_bounds__(256) void gemm_qkv_mfma(
    const ushort_t* __restrict__ xb, const ushort_t* __restrict__ wt,
    ushort_t* __restrict__ qf, ushort_t* __restrict__ kf,
    ushort_t* __restrict__ vf) {
  __shared__ ushort_t At[128 * 64];
  __shared__ ushort_t Bt[128 * 64];
  const int tid = threadIdx.x;
  const int wave = tid >> 6, lane = tid & 63;
  const int quad = lane >> 4, l16 = lane & 15;
  const int m0 = blockIdx.y * 128, n0 = blockIdx.x * 128;
  const int wm = (wave & 1) * 64, wn = (wave >> 1) * 64;
  const int key = (l16 >> 1) & 3;
  const int ntiles = (n0 >= 1280) ? 16 : 32;

  f32x4 acc[4][4];
#pragma unroll
  for (int i = 0; i < 4; i++)
#pragma unroll
    for (int j = 0; j < 4; j++) acc[i][j] = (f32x4){0.f, 0.f, 0.f, 0.f};

  const int rA = wave * 32 + (lane >> 3);
  const int cA = (lane & 7) * 8;
  const ushort_t* gA = xb + (size_t)(m0 + rA) * KS2 + cA;
  const ushort_t* gB = wt + (size_t)(n0 + rA) * KS2 + cA;

  for (int kt = 0; kt < ntiles; kt++) {
    const int ca = kt * 64;                         // A walks hi then lo
    const int cb = (kt < 16 ? kt : kt - 16) * 64;   // B wraps within hi
    __syncthreads();
#pragma unroll
    for (int j = 0; j < 4; j++) {
      GLD_LDS16(gA + ca + (size_t)(8 * j) * KS2, &At[(wave * 32 + 8 * j) * 64]);
      GLD_LDS16(gB + cb + (size_t)(8 * j) * KS2, &Bt[(wave * 32 + 8 * j) * 64]);
    }
    __syncthreads();

#pragma unroll
    for (int s = 0; s < 2; s++) {
      const int off = s * 32 + ((quad ^ key) * 8);
      short8 af[4], bf[4];
#pragma unroll
      for (int i = 0; i < 4; i++)
        af[i] = *(const short8*)&At[(wm + 16 * i + l16) * 64 + off];
#pragma unroll
      for (int j = 0; j < 4; j++)
        bf[j] = *(const short8*)&Bt[(wn + 16 * j + l16) * 64 + off];
#pragma unroll
      for (int i = 0; i < 4; i++)
#pragma unroll
        for (int j = 0; j < 4; j++)
          acc[i][j] = __builtin_amdgcn_mfma_f32_16x16x32_bf16(
              af[i], bf[j], acc[i][j], 0, 0, 0);
    }
  }

  const int b = m0 >> 11;   // whole block shares one batch (128 | 2048)

  if (n0 >= 1280) {
    // ---- fused vscatter: bf16 cast + PV B-fragment layout store ----
    const int g = (n0 - 1280) >> 7;
    ushort_t* vg = vf + (size_t)(b * 4 + g) * 262144;
#pragma unroll
    for (int i = 0; i < 4; i++) {
      int mbase = m0 + wm + 16 * i + quad * 4;
#pragma unroll
      for (int jn = 0; jn < 4; jn++) {
        int nv = (wn >> 4) + jn;
#pragma unroll
        for (int r = 0; r < 4; r++) {
          int t = (mbase + r) & 2047;
          int tk = t >> 6, ks = (t >> 5) & 1, qd = (t >> 3) & 3, jj = t & 7;
          size_t off = ((size_t)(tk * 16 + ks * 8 + nv) * 4 + qd) * 128 +
                       l16 * 8 + jj;
          vg[off] = f2bf(acc[i][jn][r]);
        }
      }
    }
  } else {
    // ---- fused RoPE + qk-norm + fragment store ----
    const int headn = n0 + wn;            // 64-aligned: one head per wave
    const bool isq = headn < 1024;
    ushort_t* dstbase = isq
        ? qf + (size_t)(b * 16 + (headn >> 6)) * 131072
        : kf + (size_t)(b * 4 + ((headn - 1024) >> 6)) * 131072;
    const float c0 = 0.4152410118074239f;          // log2(10000)/32
    const float inv_lo = exp2f(-(float)l16 * c0);
    const float inv_hi = exp2f(-(float)(16 + l16) * c0);
    const int jj = l16 & 7;

#pragma unroll
    for (int i = 0; i < 4; i++) {
#pragma unroll
      for (int r = 0; r < 4; r++) {
        int t = (m0 + wm + 16 * i + quad * 4 + r) & 2047;
        float sn0, cs0, sn1, cs1;
        __sincosf((float)t * inv_lo, &sn0, &cs0);
        __sincosf((float)t * inv_hi, &sn1, &cs1);
        // d = 16*j + l16; partner d^32 -> register j^2 (same lane)
        float rv0 = acc[i][0][r] * cs0 - acc[i][2][r] * sn0;   // d in [0,16)
        float rv1 = acc[i][1][r] * cs1 - acc[i][3][r] * sn1;   // d in [16,32)
        float rv2 = acc[i][2][r] * cs0 + acc[i][0][r] * sn0;   // d in [32,48)
        float rv3 = acc[i][3][r] * cs1 + acc[i][1][r] * sn1;   // d in [48,64)
        float ss = rv0 * rv0 + rv1 * rv1 + rv2 * rv2 + rv3 * rv3;
        ss += __shfl_xor(ss, 1, 64);
        ss += __shfl_xor(ss, 2, 64);
        ss += __shfl_xor(ss, 4, 64);
        ss += __shfl_xor(ss, 8, 64);
        float sc = 1.0f / (sqrtf(ss) + 1e-6f);
        int kt8 = t >> 6, tt = t & 63;
        int l16v = tt & 15, nt = tt >> 4;
        float rv[4] = {rv0, rv1, rv2, rv3};
#pragma unroll
        for (int j = 0; j < 4; j++) {
          int ks = j >> 1;
          int qd = (2 * j + (l16 >> 3)) & 3;
          size_t idx512 = isq ? (size_t)(kt8 * 8 + nt * 2 + ks)
                              : (size_t)(kt8 * 8 + ks * 4 + nt);
          dstbase[idx512 * 512 + qd * 128 + l16v * 8 + jj] = f2bf(rv[j] * sc);
        }
      }
    }
  }
}

// ---------------------------------------------------------------------------
// Kernel 3: bf16-MFMA causal flash attention, fixed-max softmax (m = gsc).
// ROUND 16: T14 async-STAGE split — REGISTER staging replaces
// global_load_lds.  Tile kt+1 is loaded into 6x short8 regs at the TOP of
// iteration kt (24KB/block, 96B/thread, coalesced; LDS image is linear in
// the global layout so it's a flat copy), compute runs from LDS, then
// barrier -> ds_write regs->LDS -> barrier.  The vmcnt wait lands after
// ~2000cy of compute instead of immediately (the r8/r10 structure exposed
// the full L2 latency between its two staging barriers every iteration).
// __syncthreads is a memory fence, so the compiler cannot sink the global
// loads past it — issue stays early by construction.  Barrier count
// unchanged; LDS unchanged (33.3KB, 4 blocks/CU declared).
// ---------------------------------------------------------------------------
__global__ __launch_bounds__(256, 4) void attn(
    const ushort_t* __restrict__ qf, const ushort_t* __restrict__ kf,
    const ushort_t* __restrict__ vf, const float* __restrict__ lobo,
    const float* __restrict__ qknf, float* __restrict__ y) {
  const int f = blockIdx.x;            // 1024 blocks
  const int bh = f & 31;
  const int slot = f >> 5;             // 0..31
  int tq;
  if (slot < 8)       tq = 31 - slot;  // 31..24
  else if (slot < 16) tq = 8 + slot;   // 16..23
  else if (slot < 24) tq = 31 - slot;  // 15..8
  else                tq = slot - 24;  // 0..7
  const int b = bh >> 4;
  const int h = bh & 15;
  const int g = h >> 2;

  __shared__ ushort_t KV[12288];       // [K: 8 x 512 | V: 16 x 512] per kt
  __shared__ ushort_t Ps[4 * 1088];    // per-wave 16 rows x 68

  const int tid = threadIdx.x;
  const int wave = tid >> 6, lane = tid & 63;
  const int quad = lane >> 4, l16 = lane & 15;
  ushort_t* PsW = &Ps[wave * 1088];

  short8 bones;
  {
    short bv = (l16 == 0) ? (short)0x3F80 : (short)0;
#pragma unroll
    for (int j = 0; j < 8; j++) bones[j] = bv;
  }

  const ushort_t* qbase = qf + (size_t)(b * 16 + h) * 131072 + lane * 8;
  short8 aq0 = *(const short8*)&qbase[(size_t)(tq * 8 + wave * 2 + 0) * 512];
  short8 aq1 = *(const short8*)&qbase[(size_t)(tq * 8 + wave * 2 + 1) * 512];

  f32x4 o[9];
#pragma unroll
  for (int nv = 0; nv < 9; nv++) o[nv] = (f32x4){0.f, 0.f, 0.f, 0.f};

  const float gsc = qknf[0];
  const float sinkp = __expf(lobo[h] - gsc);

  const int row = tq * 64 + wave * 16 + quad * 4;   // +r

  const ushort_t* kbase = kf + (size_t)(b * 4 + g) * 131072;
  const ushort_t* vbase = vf + (size_t)(b * 4 + g) * 262144;

  // register staging: thread owns 6 x 16B chunks of the 24KB tile
  short8 st0, st1, st2, st3, st4, st5;
#define LOAD_TILE(ktv)                                                    \
  {                                                                       \
    const ushort_t* kq = kbase + (size_t)(ktv) * 4096;                    \
    const ushort_t* vq = vbase + (size_t)(ktv) * 8192;                    \
    st0 = *(const short8*)&kq[tid * 8];                                   \
    st1 = *(const short8*)&kq[(256 + tid) * 8];                           \
    st2 = *(const short8*)&vq[tid * 8];                                   \
    st3 = *(const short8*)&vq[(256 + tid) * 8];                           \
    st4 = *(const short8*)&vq[(512 + tid) * 8];                           \
    st5 = *(const short8*)&vq[(768 + tid) * 8];                           \
  }
#define WRITE_TILE()                                                      \
  {                                                                       \
    *(short8*)&KV[tid * 8] = st0;                                         \
    *(short8*)&KV[(256 + tid) * 8] = st1;                                 \
    *(short8*)&KV[4096 + tid * 8] = st2;                                  \
    *(short8*)&KV[4096 + (256 + tid) * 8] = st3;                          \
    *(short8*)&KV[4096 + (512 + tid) * 8] = st4;                          \
    *(short8*)&KV[4096 + (768 + tid) * 8] = st5;                          \
  }

  // prologue: tile 0 into regs, then LDS
  LOAD_TILE(0);
  WRITE_TILE();
  __syncthreads();

  for (int kt = 0; kt <= tq; kt++) {
    // ---- issue next tile's global loads into regs (latency hides under
    //      the compute below; fence at the barrier keeps issue early) ----
    if (kt < tq) LOAD_TILE(kt + 1);

    // ---- QK: K frags from LDS in two batches of 4 ----
    f32x4 s[4];
#pragma unroll
    for (int nt = 0; nt < 4; nt++) s[nt] = (f32x4){0.f, 0.f, 0.f, 0.f};
    {
      short8 kb[4];
#pragma unroll
      for (int u = 0; u < 4; u++)
        kb[u] = *(const short8*)&KV[u * 512 + lane * 8];
      __builtin_amdgcn_s_setprio(1);
#pragma unroll
      for (int nt = 0; nt < 4; nt++)
        s[nt] = __builtin_amdgcn_mfma_f32_16x16x32_bf16(aq0, kb[nt], s[nt], 0, 0, 0);
      __builtin_amdgcn_s_setprio(0);
#pragma unroll
      for (int u = 0; u < 4; u++)
        kb[u] = *(const short8*)&KV[(4 + u) * 512 + lane * 8];
      __builtin_amdgcn_s_setprio(1);
#pragma unroll
      for (int nt = 0; nt < 4; nt++)
        s[nt] = __builtin_amdgcn_mfma_f32_16x16x32_bf16(aq1, kb[nt], s[nt], 0, 0, 0);
      __builtin_amdgcn_s_setprio(0);
    }

    // ---- mask + exp + bf16 store; causal cmp only on diagonal iter ----
    if (kt == tq) {
#pragma unroll
      for (int nt = 0; nt < 4; nt++) {
        int key = kt * 64 + l16 + nt * 16;
#pragma unroll
        for (int r = 0; r < 4; r++) {
          float pv = (key <= row + r) ? __expf(fmaf(s[nt][r], gsc, -gsc)) : 0.f;
          PsW[(quad * 4 + r) * 68 + nt * 16 + l16] = f2bf_hw(pv);
        }
      }
    } else {
#pragma unroll
      for (int nt = 0; nt < 4; nt++)
#pragma unroll
        for (int r = 0; r < 4; r++)
          PsW[(quad * 4 + r) * 68 + nt * 16 + l16] =
              f2bf_hw(__expf(fmaf(s[nt][r], gsc, -gsc)));
    }

    // ---- read P fragments, PV with V frags from LDS (4 batches of 4) ----
    short8 ap0 = *(const short8*)&PsW[l16 * 68 + quad * 8];
    short8 ap1 = *(const short8*)&PsW[l16 * 68 + 32 + quad * 8];
    {
      short8 vb[4];
#pragma unroll
      for (int u = 0; u < 4; u++)
        vb[u] = *(const short8*)&KV[4096 + u * 512 + lane * 8];
      __builtin_amdgcn_s_setprio(1);
#pragma unroll
      for (int nv = 0; nv < 4; nv++)
        o[nv] = __builtin_amdgcn_mfma_f32_16x16x32_bf16(ap0, vb[nv], o[nv], 0, 0, 0);
      __builtin_amdgcn_s_setprio(0);
#pragma unroll
      for (int u = 0; u < 4; u++)
        vb[u] = *(const short8*)&KV[4096 + (4 + u) * 512 + lane * 8];
      __builtin_amdgcn_s_setprio(1);
#pragma unroll
      for (int nv = 0; nv < 4; nv++)
        o[4 + nv] = __builtin_amdgcn_mfma_f32_16x16x32_bf16(ap0, vb[nv], o[4 + nv], 0, 0, 0);
      o[8] = __builtin_amdgcn_mfma_f32_16x16x32_bf16(ap0, bones, o[8], 0, 0, 0);
      o[8] = __builtin_amdgcn_mfma_f32_16x16x32_bf16(ap1, bones, o[8], 0, 0, 0);
      __builtin_amdgcn_s_setprio(0);
#pragma unroll
      for (int u = 0; u < 4; u++)
        vb[u] = *(const short8*)&KV[4096 + (8 + u) * 512 + lane * 8];
      __builtin_amdgcn_s_setprio(1);
#pragma unroll
      for (int nv = 0; nv < 4; nv++)
        o[nv] = __builtin_amdgcn_mfma_f32_16x16x32_bf16(ap1, vb[nv], o[nv], 0, 0, 0);
      __builtin_amdgcn_s_setprio(0);
#pragma unroll
      for (int u = 0; u < 4; u++)
        vb[u] = *(const short8*)&KV[4096 + (12 + u) * 512 + lane * 8];
      __builtin_amdgcn_s_setprio(1);
#pragma unroll
      for (int nv = 0; nv < 4; nv++)
        o[4 + nv] = __builtin_amdgcn_mfma_f32_16x16x32_bf16(ap1, vb[nv], o[4 + nv], 0, 0, 0);
      __builtin_amdgcn_s_setprio(0);
    }

    // ---- swap in next tile: reads done -> write regs -> visible ----
    if (kt < tq) {
      __syncthreads();   // all waves' KV reads complete
      WRITE_TILE();      // vmcnt wait here (covered by compute above)
      __syncthreads();   // new tile visible
    }
  }

  // epilogue: l = sink + mfma row-sum (col 0 of o[8]); normalize; head-sum
#pragma unroll
  for (int r = 0; r < 4; r++) {
    float lm = __shfl(o[8][r], lane & 48, 64);
    float invl = 1.0f / (lm + sinkp);
    size_t gRow = (size_t)b * T_ + row + r;
#pragma unroll
    for (int nv = 0; nv < 8; nv++)
      atomicAdd(&y[gRow * 128 + nv * 16 + l16], o[nv][r] * invl);
  }
#undef LOAD_TILE
#undef WRITE_TILE
}

// ---------------------------------------------------------------------------
// Kernel 4: out = y[4096][128] @ Wproj[128][1024] via bf16 MFMA.
// ---------------------------------------------------------------------------
__global__ __launch_bounds__(256) void out_proj(
    const float* __restrict__ y, const ushort_t* __restrict__ wpf,
    float* __restrict__ out) {
  __shared__ ushort_t yl[128 * 136];
  const int tid = threadIdx.x;
  const int wave = tid >> 6, lane = tid & 63;
  const int quad = lane >> 4, l16 = lane & 15;
  const int n0 = blockIdx.x * 128, m0 = blockIdx.y * 128;
  const int wm = (wave & 1) * 64, wn = (wave >> 1) * 64;

#pragma unroll
  for (int it = 0; it < 8; it++) {
    int p = it * 256 + tid;
    int row = p >> 4, c8 = p & 15;
    const float* src = &y[(size_t)(m0 + row) * 128 + c8 * 8];
    float4 v0 = *(const float4*)&src[0];
    float4 v1 = *(const float4*)&src[4];
    float fv[8] = {v0.x, v0.y, v0.z, v0.w, v1.x, v1.y, v1.z, v1.w};
    short8 hv;
#pragma unroll
    for (int c = 0; c < 8; c++) hv[c] = (short)f2bf(fv[c]);
    *(short8*)&yl[row * 136 + c8 * 8] = hv;
  }
  __syncthreads();

  f32x4 acc[4][4];
#pragma unroll
  for (int i = 0; i < 4; i++)
#pragma unroll
    for (int j = 0; j < 4; j++) acc[i][j] = (f32x4){0.f, 0.f, 0.f, 0.f};

#pragma unroll
  for (int ks = 0; ks < 4; ks++) {
    short8 af[4], bfr[4];
#pragma unroll
    for (int i = 0; i < 4; i++)
      af[i] = *(const short8*)&yl[(wm + 16 * i + l16) * 136 + (ks * 4 + quad) * 8];
    const ushort_t* wb = wpf + (((size_t)(n0 >> 7) * 4 + ks) * 8) * 512;
#pragma unroll
    for (int j = 0; j < 4; j++)
      bfr[j] = *(const short8*)&wb[((size_t)((wn >> 4) + j)) * 512 + lane * 8];
#pragma unroll
    for (int i = 0; i < 4; i++)
#pragma unroll
      for (int j = 0; j < 4; j++)
        acc[i][j] = __builtin_amdgcn_mfma_f32_16x16x32_bf16(
            af[i], bfr[j], acc[i][j], 0, 0, 0);
  }

#pragma unroll
  for (int i = 0; i < 4; i++) {
    int m = m0 + wm + 16 * i + quad * 4;
#pragma unroll
    for (int j = 0; j < 4; j++) {
      int n = n0 + wn + 16 * j + l16;
#pragma unroll
      for (int r = 0; r < 4; r++)
        out[(size_t)(m + r) * 1024 + n] = acc[i][j][r];
    }
  }
}

// ---------------------------------------------------------------------------
extern "C" void kernel_launch(void* const* d_in, const int* in_sizes, int n_in,
                              void* d_out, int out_size, void* d_ws, size_t ws_size,
                              hipStream_t stream) {
  const float* x     = (const float*)d_in[0];
  const float* Wq    = (const float*)d_in[2];
  const float* Wk    = (const float*)d_in[3];
  const float* Wv    = (const float*)d_in[4];
  const float* Wproj = (const float*)d_in[5];
  const float* lobo  = (const float*)d_in[6];
  const float* qknf  = (const float*)d_in[7];
  float* out = (float*)d_out;

  // ws layout (footprint unchanged; qkv f32 intermediate eliminated):
  //  [0, 8.39MB)    qf bf16 (4,194,304) — written by gemm, read by attn
  //  [8.39, 10.49)  kf bf16 (1,048,576)
  //  [10.49, 14.68) vf bf16 (2,097,152)
  //  [14.68, 16.78) y  f32  (524,288) — zeroed by prep, atomics by attn
  //  [29.36, 46.14) xb bf16 (8,388,608) — written by prep, read by gemm
  //  [46.14, 53.48) wt bf16;  [53.48, 53.74) wpf bf16
  //  All producer->consumer pairs disjoint: no intra-kernel aliases.
  ushort_t* qf = (ushort_t*)d_ws;                                 // 4,194,304
  ushort_t* kf = qf + (size_t)B_ * H_ * T_ * 64;                  // 1,048,576
  ushort_t* vf = kf + (size_t)B_ * G_ * T_ * 64;                  // 2,097,152
  float* y = (float*)(vf + (size_t)B_ * G_ * T_ * 128);           //   524,288 f32
  ushort_t* xb = (ushort_t*)((float*)d_ws + (size_t)B_ * T_ * NQKV);  // 8,388,608
  ushort_t* wt = xb + (size_t)B_ * T_ * KS2;                      // 3,670,016
  ushort_t* wpf = wt + (size_t)NQKV * KS2;                        //   131,072

  // 4 dispatches: prep(+y-zero) -> gemm(+rope+vscatter) -> attn -> out_proj
  prep<<<3072, 256, 0, stream>>>(x, Wq, Wk, Wv, Wproj, xb, wt, wpf, y);

  dim3 gg(NQKV / 128, (B_ * T_) / 128);
  gemm_qkv_mfma<<<gg, 256, 0, stream>>>(xb, wt, qf, kf, vf);

  attn<<<B_ * H_ * 32, 256, 0, stream>>>(qf, kf, vf, lobo, qknf, y);

  dim3 go(8, 32);
  out_proj<<<go, 256, 0, stream>>>(y, wpf, out);
}

// Round 17
// 197.661 us; speedup vs baseline: 1.0198x; 1.0198x over previous
//
#include <hip/hip_runtime.h>
#include <hip/hip_bf16.h>
#include <math.h>

#define B_ 2
#define T_ 2048
#define C_ 1024
#define H_ 16
#define G_ 4
#define DQK_ 64
#define DV_ 128
#define NQKV 1792   // H*DQK + G*DQK + G*DV
#define KS2 2048    // compact split storage: [hi | lo]
// Variable-K split GEMM: Q/K columns (n<1280) use 2048 K-depth
// (hi·hi + lo·hi); V columns (n>=1280) use 1024 (hi·hi only).
// Operand rows chunk-XOR-swizzled: chunk c of row r at phys chunk c^((r>>1)&3).

typedef __attribute__((ext_vector_type(8))) short short8;
typedef __attribute__((ext_vector_type(4))) float f32x4;
typedef unsigned short ushort_t;

__device__ inline ushort_t f2bf(float f) {
  union { float f; unsigned int u; } v; v.f = f;
  unsigned int r = (v.u + 0x7FFFu + ((v.u >> 16) & 1u)) >> 16;  // RNE
  return (ushort_t)r;
}
__device__ inline float bf2f(ushort_t h) {
  union { unsigned int u; float f; } v; v.u = ((unsigned int)h) << 16;
  return v.f;
}
// single-instruction RNE f32->bf16 (dst.lo = cvt(src)); P is finite in (0,1]
__device__ inline ushort_t f2bf_hw(float f) {
  unsigned int u;
  asm("v_cvt_pk_bf16_f32 %0, %1, %1" : "=v"(u) : "v"(f));
  return (ushort_t)u;
}

#define GLD_LDS16(g, l)                                              \
  __builtin_amdgcn_global_load_lds(                                  \
      (const __attribute__((address_space(1))) void*)(g),            \
      (__attribute__((address_space(3))) void*)(l), 16, 0, 0)

// ---------------------------------------------------------------------------
// Kernel 0 (FUSED): prep = cast_x | cast_w | cast_wp | y-zero by range.
// ---------------------------------------------------------------------------
__global__ __launch_bounds__(256) void prep(
    const float* __restrict__ x, const float* __restrict__ Wq,
    const float* __restrict__ Wk, const float* __restrict__ Wv,
    const float* __restrict__ Wproj, ushort_t* __restrict__ xb,
    ushort_t* __restrict__ wt, ushort_t* __restrict__ wpf,
    float* __restrict__ y) {
  __shared__ float tile[64][65];
  const int bid = blockIdx.x;
  const int tid = threadIdx.x;

  if (bid < 2048) {
    // ---- cast_x ----
    int idx = bid * 256 + tid;   // 524288
    int m = idx >> 7;
    int c8 = idx & 127;
    const float* src = &x[(size_t)m * 1024 + c8 * 8];
    float4 v0 = *(const float4*)&src[0];
    float4 v1 = *(const float4*)&src[4];
    float f[8] = {v0.x, v0.y, v0.z, v0.w, v1.x, v1.y, v1.z, v1.w};
    short8 hv, lv;
#pragma unroll
    for (int c = 0; c < 8; c++) {
      ushort_t h = f2bf(f[c]);
      hv[c] = (short)h;
      lv[c] = (short)f2bf(f[c] - bf2f(h));
    }
    int key = (m >> 1) & 3;
    int phys = (c8 & ~3) * 8 + ((c8 & 3) ^ key) * 8;
    ushort_t* row = xb + (size_t)m * KS2;
    *(short8*)&row[phys] = hv;
    *(short8*)&row[1024 + phys] = lv;
  } else if (bid < 2496) {
    // ---- cast_w ----
    const int wid = bid - 2048;          // 0..447 = 28 x 16
    const int n0 = (wid % 28) * 64;
    const int k0 = (wid / 28) * 64;

    const float* Wp; int ldw, noff;
    if (n0 < 1024)      { Wp = Wq; ldw = 1024; noff = n0; }
    else if (n0 < 1280) { Wp = Wk; ldw = 256;  noff = n0 - 1024; }
    else                { Wp = Wv; ldw = 512;  noff = n0 - 1280; }

#pragma unroll
    for (int it = 0; it < 4; it++) {
      int fi = it * 256 + tid;
      int kk = fi >> 4;
      int nc = (fi & 15) * 4;
      float4 v = *(const float4*)&Wp[(size_t)(k0 + kk) * ldw + noff + nc];
      tile[nc + 0][kk] = v.x; tile[nc + 1][kk] = v.y;
      tile[nc + 2][kk] = v.z; tile[nc + 3][kk] = v.w;
    }
    __syncthreads();
    int nn = tid >> 2, seg = tid & 3;
    int n = n0 + nn;
    int key = (n >> 1) & 3;
    ushort_t* row = wt + (size_t)n * KS2;
#pragma unroll
    for (int j = 0; j < 2; j++) {
      short8 hv;
#pragma unroll
      for (int u = 0; u < 8; u++)
        hv[u] = (short)f2bf(tile[nn][seg * 16 + j * 8 + u]);
      int c8 = (k0 >> 3) + seg * 2 + j;
      int phys = (c8 & ~3) * 8 + ((c8 & 3) ^ key) * 8;
      *(short8*)&row[phys] = hv;
    }
  } else if (bid < 2560) {
    // ---- cast_wp ----
    int idx = (bid - 2496) * 256 + tid;  // 16384
    int n = idx & 1023;
    int kc = idx >> 10;                  // 0..15 (chunk of 8 k's)
    short8 v;
#pragma unroll
    for (int j = 0; j < 8; j++)
      v[j] = (short)f2bf(Wproj[(size_t)(kc * 8 + j) * 1024 + n]);
    size_t off = (((size_t)(n >> 7) * 4 + (kc >> 2)) * 8 + ((n >> 4) & 7)) * 512 +
                 ((kc & 3) * 16 + (n & 15)) * 8;
    *(short8*)&wpf[off] = v;
  } else {
    // ---- zero y (y does not alias xb; safe to zero here) ----
    int idx = (bid - 2560) * 256 + tid;   // 131072 float4s
    *(float4*)&y[(size_t)idx * 4] = (float4){0.f, 0.f, 0.f, 0.f};
  }
}

// ---------------------------------------------------------------------------
// Kernel 1: bf16-MFMA QKV GEMM, BK=64, fully fused epilogue (r15 proven):
// V-cols -> vf PV-fragment store; Q/K-cols -> in-register RoPE + qk-norm +
// fragment store to qf/kf.  qkv f32 intermediate eliminated.
// ---------------------------------------------------------------------------
__global__ __launch_bounds__(256) void gemm_qkv_mfma(
    const ushort_t* __restrict__ xb, const ushort_t* __restrict__ wt,
    ushort_t* __restrict__ qf, ushort_t* __restrict__ kf,
    ushort_t* __restrict__ vf) {
  __shared__ ushort_t At[128 * 64];
  __shared__ ushort_t Bt[128 * 64];
  const int tid = threadIdx.x;
  const int wave = tid >> 6, lane = tid & 63;
  const int quad = lane >> 4, l16 = lane & 15;
  const int m0 = blockIdx.y * 128, n0 = blockIdx.x * 128;
  const int wm = (wave & 1) * 64, wn = (wave >> 1) * 64;
  const int key = (l16 >> 1) & 3;
  const int ntiles = (n0 >= 1280) ? 16 : 32;

  f32x4 acc[4][4];
#pragma unroll
  for (int i = 0; i < 4; i++)
#pragma unroll
    for (int j = 0; j < 4; j++) acc[i][j] = (f32x4){0.f, 0.f, 0.f, 0.f};

  const int rA = wave * 32 + (lane >> 3);
  const int cA = (lane & 7) * 8;
  const ushort_t* gA = xb + (size_t)(m0 + rA) * KS2 + cA;
  const ushort_t* gB = wt + (size_t)(n0 + rA) * KS2 + cA;

  for (int kt = 0; kt < ntiles; kt++) {
    const int ca = kt * 64;                         // A walks hi then lo
    const int cb = (kt < 16 ? kt : kt - 16) * 64;   // B wraps within hi
    __syncthreads();
#pragma unroll
    for (int j = 0; j < 4; j++) {
      GLD_LDS16(gA + ca + (size_t)(8 * j) * KS2, &At[(wave * 32 + 8 * j) * 64]);
      GLD_LDS16(gB + cb + (size_t)(8 * j) * KS2, &Bt[(wave * 32 + 8 * j) * 64]);
    }
    __syncthreads();

#pragma unroll
    for (int s = 0; s < 2; s++) {
      const int off = s * 32 + ((quad ^ key) * 8);
      short8 af[4], bf[4];
#pragma unroll
      for (int i = 0; i < 4; i++)
        af[i] = *(const short8*)&At[(wm + 16 * i + l16) * 64 + off];
#pragma unroll
      for (int j = 0; j < 4; j++)
        bf[j] = *(const short8*)&Bt[(wn + 16 * j + l16) * 64 + off];
#pragma unroll
      for (int i = 0; i < 4; i++)
#pragma unroll
        for (int j = 0; j < 4; j++)
          acc[i][j] = __builtin_amdgcn_mfma_f32_16x16x32_bf16(
              af[i], bf[j], acc[i][j], 0, 0, 0);
    }
  }

  const int b = m0 >> 11;   // whole block shares one batch (128 | 2048)

  if (n0 >= 1280) {
    // ---- fused vscatter: bf16 cast + PV B-fragment layout store ----
    const int g = (n0 - 1280) >> 7;
    ushort_t* vg = vf + (size_t)(b * 4 + g) * 262144;
#pragma unroll
    for (int i = 0; i < 4; i++) {
      int mbase = m0 + wm + 16 * i + quad * 4;
#pragma unroll
      for (int jn = 0; jn < 4; jn++) {
        int nv = (wn >> 4) + jn;
#pragma unroll
        for (int r = 0; r < 4; r++) {
          int t = (mbase + r) & 2047;
          int tk = t >> 6, ks = (t >> 5) & 1, qd = (t >> 3) & 3, jj = t & 7;
          size_t off = ((size_t)(tk * 16 + ks * 8 + nv) * 4 + qd) * 128 +
                       l16 * 8 + jj;
          vg[off] = f2bf(acc[i][jn][r]);
        }
      }
    }
  } else {
    // ---- fused RoPE + qk-norm + fragment store ----
    const int headn = n0 + wn;            // 64-aligned: one head per wave
    const bool isq = headn < 1024;
    ushort_t* dstbase = isq
        ? qf + (size_t)(b * 16 + (headn >> 6)) * 131072
        : kf + (size_t)(b * 4 + ((headn - 1024) >> 6)) * 131072;
    const float c0 = 0.4152410118074239f;          // log2(10000)/32
    const float inv_lo = exp2f(-(float)l16 * c0);
    const float inv_hi = exp2f(-(float)(16 + l16) * c0);
    const int jj = l16 & 7;

#pragma unroll
    for (int i = 0; i < 4; i++) {
#pragma unroll
      for (int r = 0; r < 4; r++) {
        int t = (m0 + wm + 16 * i + quad * 4 + r) & 2047;
        float sn0, cs0, sn1, cs1;
        __sincosf((float)t * inv_lo, &sn0, &cs0);
        __sincosf((float)t * inv_hi, &sn1, &cs1);
        // d = 16*j + l16; partner d^32 -> register j^2 (same lane)
        float rv0 = acc[i][0][r] * cs0 - acc[i][2][r] * sn0;   // d in [0,16)
        float rv1 = acc[i][1][r] * cs1 - acc[i][3][r] * sn1;   // d in [16,32)
        float rv2 = acc[i][2][r] * cs0 + acc[i][0][r] * sn0;   // d in [32,48)
        float rv3 = acc[i][3][r] * cs1 + acc[i][1][r] * sn1;   // d in [48,64)
        float ss = rv0 * rv0 + rv1 * rv1 + rv2 * rv2 + rv3 * rv3;
        ss += __shfl_xor(ss, 1, 64);
        ss += __shfl_xor(ss, 2, 64);
        ss += __shfl_xor(ss, 4, 64);
        ss += __shfl_xor(ss, 8, 64);
        float sc = 1.0f / (sqrtf(ss) + 1e-6f);
        int kt8 = t >> 6, tt = t & 63;
        int l16v = tt & 15, nt = tt >> 4;
        float rv[4] = {rv0, rv1, rv2, rv3};
#pragma unroll
        for (int j = 0; j < 4; j++) {
          int ks = j >> 1;
          int qd = (2 * j + (l16 >> 3)) & 3;
          size_t idx512 = isq ? (size_t)(kt8 * 8 + nt * 2 + ks)
                              : (size_t)(kt8 * 8 + ks * 4 + nt);
          dstbase[idx512 * 512 + qd * 128 + l16v * 8 + jj] = f2bf(rv[j] * sc);
        }
      }
    }
  }
}

// ---------------------------------------------------------------------------
// Kernel 3: bf16-MFMA causal flash attention (ROUND-15 BODY, proven 66.0us)
// + ROUND 17: XCD-PINNED block decode.  blockIdx%8 == (b*4+g), so all 128
// blocks sharing one K/V group land on ONE XCD (assuming round-robin
// blockIdx->XCD dispatch).  Per-XCD working set: 1.5MB KV + ~2MB Q < 4MB L2
// -> staging loads become L2 hits (were HBM misses under thrashing),
// cutting the exposed ~900cy drain latency to ~200cy.
// Decode: grp=f&7 -> (b,g); rest=f>>3; h=g*4+(rest&3); si=rest>>2 with the
// serpentine tq map (per-CU iteration sum stays exactly 66: for s'=c>>2 the
// resident set is {31-s', 16+s', 15-s', s'}).  Compute body unchanged.
// ---------------------------------------------------------------------------
__global__ __launch_bounds__(256, 4) void attn(
    const ushort_t* __restrict__ qf, const ushort_t* __restrict__ kf,
    const ushort_t* __restrict__ vf, const float* __restrict__ lobo,
    const float* __restrict__ qknf, float* __restrict__ y) {
  const int f = blockIdx.x;            // 1024 blocks
  const int grp = f & 7;               // XCD-pinned K/V group
  const int b = grp >> 2;
  const int g = grp & 3;
  const int rest = f >> 3;             // 0..127 within group
  const int h = g * 4 + (rest & 3);
  const int si = rest >> 2;            // 0..31
  int tq;
  if (si < 8)       tq = 31 - si;      // 31..24
  else if (si < 16) tq = 8 + si;       // 16..23
  else if (si < 24) tq = 31 - si;      // 15..8
  else              tq = si - 24;      // 0..7

  __shared__ ushort_t KV[12288];       // [K: 8 x 512 | V: 16 x 512] per kt
  __shared__ ushort_t Ps[4 * 1088];    // per-wave 16 rows x 68

  const int tid = threadIdx.x;
  const int wave = tid >> 6, lane = tid & 63;
  const int quad = lane >> 4, l16 = lane & 15;
  ushort_t* PsW = &Ps[wave * 1088];

  short8 bones;
  {
    short bv = (l16 == 0) ? (short)0x3F80 : (short)0;
#pragma unroll
    for (int j = 0; j < 8; j++) bones[j] = bv;
  }

  const ushort_t* qbase = qf + (size_t)(b * 16 + h) * 131072 + lane * 8;
  short8 aq0 = *(const short8*)&qbase[(size_t)(tq * 8 + wave * 2 + 0) * 512];
  short8 aq1 = *(const short8*)&qbase[(size_t)(tq * 8 + wave * 2 + 1) * 512];

  f32x4 o[9];
#pragma unroll
  for (int nv = 0; nv < 9; nv++) o[nv] = (f32x4){0.f, 0.f, 0.f, 0.f};

  const float gsc = qknf[0];
  const float sinkp = __expf(lobo[h] - gsc);

  const int row = tq * 64 + wave * 16 + quad * 4;   // +r

  // per-lane global pointers for staging (lane*8 element offset built in)
  const ushort_t* kgl = kf + (size_t)(b * 4 + g) * 131072 + lane * 8;
  const ushort_t* vgl = vf + (size_t)(b * 4 + g) * 262144 + lane * 8;

  for (int kt = 0; kt <= tq; kt++) {
    // ---- stage K+V tile into LDS (barriers wrap staging ONLY) ----
    __syncthreads();   // previous iteration's KV reads complete
    {
      const ushort_t* gk = kgl + (size_t)kt * 4096;
      const ushort_t* gv = vgl + (size_t)kt * 8192;
      GLD_LDS16(gk + (wave * 2 + 0) * 512, &KV[(wave * 2 + 0) * 512]);
      GLD_LDS16(gk + (wave * 2 + 1) * 512, &KV[(wave * 2 + 1) * 512]);
#pragma unroll
      for (int j = 0; j < 4; j++)
        GLD_LDS16(gv + (wave * 4 + j) * 512, &KV[4096 + (wave * 4 + j) * 512]);
    }
    __syncthreads();   // staging complete (implicit vmcnt drain)

    // ---- QK: K frags from LDS in two batches of 4 ----
    f32x4 s[4];
#pragma unroll
    for (int nt = 0; nt < 4; nt++) s[nt] = (f32x4){0.f, 0.f, 0.f, 0.f};
    {
      short8 kb[4];
#pragma unroll
      for (int u = 0; u < 4; u++)
        kb[u] = *(const short8*)&KV[u * 512 + lane * 8];
      __builtin_amdgcn_s_setprio(1);
#pragma unroll
      for (int nt = 0; nt < 4; nt++)
        s[nt] = __builtin_amdgcn_mfma_f32_16x16x32_bf16(aq0, kb[nt], s[nt], 0, 0, 0);
      __builtin_amdgcn_s_setprio(0);
#pragma unroll
      for (int u = 0; u < 4; u++)
        kb[u] = *(const short8*)&KV[(4 + u) * 512 + lane * 8];
      __builtin_amdgcn_s_setprio(1);
#pragma unroll
      for (int nt = 0; nt < 4; nt++)
        s[nt] = __builtin_amdgcn_mfma_f32_16x16x32_bf16(aq1, kb[nt], s[nt], 0, 0, 0);
      __builtin_amdgcn_s_setprio(0);
    }

    // ---- mask + exp + bf16 store; causal cmp only on diagonal iter ----
    if (kt == tq) {
#pragma unroll
      for (int nt = 0; nt < 4; nt++) {
        int key = kt * 64 + l16 + nt * 16;
#pragma unroll
        for (int r = 0; r < 4; r++) {
          float pv = (key <= row + r) ? __expf(fmaf(s[nt][r], gsc, -gsc)) : 0.f;
          PsW[(quad * 4 + r) * 68 + nt * 16 + l16] = f2bf_hw(pv);
        }
      }
    } else {
#pragma unroll
      for (int nt = 0; nt < 4; nt++)
#pragma unroll
        for (int r = 0; r < 4; r++)
          PsW[(quad * 4 + r) * 68 + nt * 16 + l16] =
              f2bf_hw(__expf(fmaf(s[nt][r], gsc, -gsc)));
    }

    // ---- read P fragments, PV with V frags from LDS (4 batches of 4) ----
    short8 ap0 = *(const short8*)&PsW[l16 * 68 + quad * 8];
    short8 ap1 = *(const short8*)&PsW[l16 * 68 + 32 + quad * 8];
    {
      short8 vb[4];
#pragma unroll
      for (int u = 0; u < 4; u++)
        vb[u] = *(const short8*)&KV[4096 + u * 512 + lane * 8];
      __builtin_amdgcn_s_setprio(1);
#pragma unroll
      for (int nv = 0; nv < 4; nv++)
        o[nv] = __builtin_amdgcn_mfma_f32_16x16x32_bf16(ap0, vb[nv], o[nv], 0, 0, 0);
      __builtin_amdgcn_s_setprio(0);
#pragma unroll
      for (int u = 0; u < 4; u++)
        vb[u] = *(const short8*)&KV[4096 + (4 + u) * 512 + lane * 8];
      __builtin_amdgcn_s_setprio(1);
#pragma unroll
      for (int nv = 0; nv < 4; nv++)
        o[4 + nv] = __builtin_amdgcn_mfma_f32_16x16x32_bf16(ap0, vb[nv], o[4 + nv], 0, 0, 0);
      o[8] = __builtin_amdgcn_mfma_f32_16x16x32_bf16(ap0, bones, o[8], 0, 0, 0);
      o[8] = __builtin_amdgcn_mfma_f32_16x16x32_bf16(ap1, bones, o[8], 0, 0, 0);
      __builtin_amdgcn_s_setprio(0);
#pragma unroll
      for (int u = 0; u < 4; u++)
        vb[u] = *(const short8*)&KV[4096 + (8 + u) * 512 + lane * 8];
      __builtin_amdgcn_s_setprio(1);
#pragma unroll
      for (int nv = 0; nv < 4; nv++)
        o[nv] = __builtin_amdgcn_mfma_f32_16x16x32_bf16(ap1, vb[nv], o[nv], 0, 0, 0);
      __builtin_amdgcn_s_setprio(0);
#pragma unroll
      for (int u = 0; u < 4; u++)
        vb[u] = *(const short8*)&KV[4096 + (12 + u) * 512 + lane * 8];
      __builtin_amdgcn_s_setprio(1);
#pragma unroll
      for (int nv = 0; nv < 4; nv++)
        o[4 + nv] = __builtin_amdgcn_mfma_f32_16x16x32_bf16(ap1, vb[nv], o[4 + nv], 0, 0, 0);
      __builtin_amdgcn_s_setprio(0);
    }
  }

  // epilogue: l = sink + mfma row-sum (col 0 of o[8]); normalize; head-sum
#pragma unroll
  for (int r = 0; r < 4; r++) {
    float lm = __shfl(o[8][r], lane & 48, 64);
    float invl = 1.0f / (lm + sinkp);
    size_t gRow = (size_t)b * T_ + row + r;
#pragma unroll
    for (int nv = 0; nv < 8; nv++)
      atomicAdd(&y[gRow * 128 + nv * 16 + l16], o[nv][r] * invl);
  }
}

// ---------------------------------------------------------------------------
// Kernel 4: out = y[4096][128] @ Wproj[128][1024] via bf16 MFMA.
// ---------------------------------------------------------------------------
__global__ __launch_bounds__(256) void out_proj(
    const float* __restrict__ y, const ushort_t* __restrict__ wpf,
    float* __restrict__ out) {
  __shared__ ushort_t yl[128 * 136];
  const int tid = threadIdx.x;
  const int wave = tid >> 6, lane = tid & 63;
  const int quad = lane >> 4, l16 = lane & 15;
  const int n0 = blockIdx.x * 128, m0 = blockIdx.y * 128;
  const int wm = (wave & 1) * 64, wn = (wave >> 1) * 64;

#pragma unroll
  for (int it = 0; it < 8; it++) {
    int p = it * 256 + tid;
    int row = p >> 4, c8 = p & 15;
    const float* src = &y[(size_t)(m0 + row) * 128 + c8 * 8];
    float4 v0 = *(const float4*)&src[0];
    float4 v1 = *(const float4*)&src[4];
    float fv[8] = {v0.x, v0.y, v0.z, v0.w, v1.x, v1.y, v1.z, v1.w};
    short8 hv;
#pragma unroll
    for (int c = 0; c < 8; c++) hv[c] = (short)f2bf(fv[c]);
    *(short8*)&yl[row * 136 + c8 * 8] = hv;
  }
  __syncthreads();

  f32x4 acc[4][4];
#pragma unroll
  for (int i = 0; i < 4; i++)
#pragma unroll
    for (int j = 0; j < 4; j++) acc[i][j] = (f32x4){0.f, 0.f, 0.f, 0.f};

#pragma unroll
  for (int ks = 0; ks < 4; ks++) {
    short8 af[4], bfr[4];
#pragma unroll
    for (int i = 0; i < 4; i++)
      af[i] = *(const short8*)&yl[(wm + 16 * i + l16) * 136 + (ks * 4 + quad) * 8];
    const ushort_t* wb = wpf + (((size_t)(n0 >> 7) * 4 + ks) * 8) * 512;
#pragma unroll
    for (int j = 0; j < 4; j++)
      bfr[j] = *(const short8*)&wb[((size_t)((wn >> 4) + j)) * 512 + lane * 8];
#pragma unroll
    for (int i = 0; i < 4; i++)
#pragma unroll
      for (int j = 0; j < 4; j++)
        acc[i][j] = __builtin_amdgcn_mfma_f32_16x16x32_bf16(
            af[i], bfr[j], acc[i][j], 0, 0, 0);
  }

#pragma unroll
  for (int i = 0; i < 4; i++) {
    int m = m0 + wm + 16 * i + quad * 4;
#pragma unroll
    for (int j = 0; j < 4; j++) {
      int n = n0 + wn + 16 * j + l16;
#pragma unroll
      for (int r = 0; r < 4; r++)
        out[(size_t)(m + r) * 1024 + n] = acc[i][j][r];
    }
  }
}

// ---------------------------------------------------------------------------
extern "C" void kernel_launch(void* const* d_in, const int* in_sizes, int n_in,
                              void* d_out, int out_size, void* d_ws, size_t ws_size,
                              hipStream_t stream) {
  const float* x     = (const float*)d_in[0];
  const float* Wq    = (const float*)d_in[2];
  const float* Wk    = (const float*)d_in[3];
  const float* Wv    = (const float*)d_in[4];
  const float* Wproj = (const float*)d_in[5];
  const float* lobo  = (const float*)d_in[6];
  const float* qknf  = (const float*)d_in[7];
  float* out = (float*)d_out;

  // ws layout (footprint unchanged; qkv f32 intermediate eliminated):
  //  [0, 8.39MB)    qf bf16 (4,194,304) — written by gemm, read by attn
  //  [8.39, 10.49)  kf bf16 (1,048,576)
  //  [10.49, 14.68) vf bf16 (2,097,152)
  //  [14.68, 16.78) y  f32  (524,288) — zeroed by prep, atomics by attn
  //  [29.36, 46.14) xb bf16 (8,388,608) — written by prep, read by gemm
  //  [46.14, 53.48) wt bf16;  [53.48, 53.74) wpf bf16
  //  All producer->consumer pairs disjoint: no intra-kernel aliases.
  ushort_t* qf = (ushort_t*)d_ws;                                 // 4,194,304
  ushort_t* kf = qf + (size_t)B_ * H_ * T_ * 64;                  // 1,048,576
  ushort_t* vf = kf + (size_t)B_ * G_ * T_ * 64;                  // 2,097,152
  float* y = (float*)(vf + (size_t)B_ * G_ * T_ * 128);           //   524,288 f32
  ushort_t* xb = (ushort_t*)((float*)d_ws + (size_t)B_ * T_ * NQKV);  // 8,388,608
  ushort_t* wt = xb + (size_t)B_ * T_ * KS2;                      // 3,670,016
  ushort_t* wpf = wt + (size_t)NQKV * KS2;                        //   131,072

  // 4 dispatches: prep(+y-zero) -> gemm(+rope+vscatter) -> attn -> out_proj
  prep<<<3072, 256, 0, stream>>>(x, Wq, Wk, Wv, Wproj, xb, wt, wpf, y);

  dim3 gg(NQKV / 128, (B_ * T_) / 128);
  gemm_qkv_mfma<<<gg, 256, 0, stream>>>(xb, wt, qf, kf, vf);

  attn<<<B_ * H_ * 32, 256, 0, stream>>>(qf, kf, vf, lobo, qknf, y);

  dim3 go(8, 32);
  out_proj<<<go, 256, 0, stream>>>(y, wpf, out);
}

// Round 18
// 194.908 us; speedup vs baseline: 1.0342x; 1.0141x over previous
//
#include <hip/hip_runtime.h>
#include <hip/hip_bf16.h>
#include <math.h>

#define B_ 2
#define T_ 2048
#define C_ 1024
#define H_ 16
#define G_ 4
#define DQK_ 64
#define DV_ 128
#define NQKV 1792   // H*DQK + G*DQK + G*DV
#define KS2 2048    // compact split storage: [hi | lo]
// Variable-K split GEMM: Q/K columns (n<1280) use 2048 K-depth
// (hi·hi + lo·hi); V columns (n>=1280) use 1024 (hi·hi only).
// Operand rows chunk-XOR-swizzled: chunk c of row r at phys chunk c^((r>>1)&3).

typedef __attribute__((ext_vector_type(8))) short short8;
typedef __attribute__((ext_vector_type(4))) float f32x4;
typedef unsigned short ushort_t;

__device__ inline ushort_t f2bf(float f) {
  union { float f; unsigned int u; } v; v.f = f;
  unsigned int r = (v.u + 0x7FFFu + ((v.u >> 16) & 1u)) >> 16;  // RNE
  return (ushort_t)r;
}
__device__ inline float bf2f(ushort_t h) {
  union { unsigned int u; float f; } v; v.u = ((unsigned int)h) << 16;
  return v.f;
}
// single-instruction RNE f32->bf16 (dst.lo = cvt(src)); P is finite in (0,1]
__device__ inline ushort_t f2bf_hw(float f) {
  unsigned int u;
  asm("v_cvt_pk_bf16_f32 %0, %1, %1" : "=v"(u) : "v"(f));
  return (ushort_t)u;
}

#define GLD_LDS16(g, l)                                              \
  __builtin_amdgcn_global_load_lds(                                  \
      (const __attribute__((address_space(1))) void*)(g),            \
      (__attribute__((address_space(3))) void*)(l), 16, 0, 0)

// ---------------------------------------------------------------------------
// Kernel 0 (FUSED): prep = cast_x | cast_w | cast_wp | y-zero by range.
// ---------------------------------------------------------------------------
__global__ __launch_bounds__(256) void prep(
    const float* __restrict__ x, const float* __restrict__ Wq,
    const float* __restrict__ Wk, const float* __restrict__ Wv,
    const float* __restrict__ Wproj, ushort_t* __restrict__ xb,
    ushort_t* __restrict__ wt, ushort_t* __restrict__ wpf,
    float* __restrict__ y) {
  __shared__ float tile[64][65];
  const int bid = blockIdx.x;
  const int tid = threadIdx.x;

  if (bid < 2048) {
    // ---- cast_x ----
    int idx = bid * 256 + tid;   // 524288
    int m = idx >> 7;
    int c8 = idx & 127;
    const float* src = &x[(size_t)m * 1024 + c8 * 8];
    float4 v0 = *(const float4*)&src[0];
    float4 v1 = *(const float4*)&src[4];
    float f[8] = {v0.x, v0.y, v0.z, v0.w, v1.x, v1.y, v1.z, v1.w};
    short8 hv, lv;
#pragma unroll
    for (int c = 0; c < 8; c++) {
      ushort_t h = f2bf(f[c]);
      hv[c] = (short)h;
      lv[c] = (short)f2bf(f[c] - bf2f(h));
    }
    int key = (m >> 1) & 3;
    int phys = (c8 & ~3) * 8 + ((c8 & 3) ^ key) * 8;
    ushort_t* row = xb + (size_t)m * KS2;
    *(short8*)&row[phys] = hv;
    *(short8*)&row[1024 + phys] = lv;
  } else if (bid < 2496) {
    // ---- cast_w ----
    const int wid = bid - 2048;          // 0..447 = 28 x 16
    const int n0 = (wid % 28) * 64;
    const int k0 = (wid / 28) * 64;

    const float* Wp; int ldw, noff;
    if (n0 < 1024)      { Wp = Wq; ldw = 1024; noff = n0; }
    else if (n0 < 1280) { Wp = Wk; ldw = 256;  noff = n0 - 1024; }
    else                { Wp = Wv; ldw = 512;  noff = n0 - 1280; }

#pragma unroll
    for (int it = 0; it < 4; it++) {
      int fi = it * 256 + tid;
      int kk = fi >> 4;
      int nc = (fi & 15) * 4;
      float4 v = *(const float4*)&Wp[(size_t)(k0 + kk) * ldw + noff + nc];
      tile[nc + 0][kk] = v.x; tile[nc + 1][kk] = v.y;
      tile[nc + 2][kk] = v.z; tile[nc + 3][kk] = v.w;
    }
    __syncthreads();
    int nn = tid >> 2, seg = tid & 3;
    int n = n0 + nn;
    int key = (n >> 1) & 3;
    ushort_t* row = wt + (size_t)n * KS2;
#pragma unroll
    for (int j = 0; j < 2; j++) {
      short8 hv;
#pragma unroll
      for (int u = 0; u < 8; u++)
        hv[u] = (short)f2bf(tile[nn][seg * 16 + j * 8 + u]);
      int c8 = (k0 >> 3) + seg * 2 + j;
      int phys = (c8 & ~3) * 8 + ((c8 & 3) ^ key) * 8;
      *(short8*)&row[phys] = hv;
    }
  } else if (bid < 2560) {
    // ---- cast_wp ----
    int idx = (bid - 2496) * 256 + tid;  // 16384
    int n = idx & 1023;
    int kc = idx >> 10;                  // 0..15 (chunk of 8 k's)
    short8 v;
#pragma unroll
    for (int j = 0; j < 8; j++)
      v[j] = (short)f2bf(Wproj[(size_t)(kc * 8 + j) * 1024 + n]);
    size_t off = (((size_t)(n >> 7) * 4 + (kc >> 2)) * 8 + ((n >> 4) & 7)) * 512 +
                 ((kc & 3) * 16 + (n & 15)) * 8;
    *(short8*)&wpf[off] = v;
  } else {
    // ---- zero y (y does not alias xb; safe to zero here) ----
    int idx = (bid - 2560) * 256 + tid;   // 131072 float4s
    *(float4*)&y[(size_t)idx * 4] = (float4){0.f, 0.f, 0.f, 0.f};
  }
}

// ---------------------------------------------------------------------------
// Kernel 1: bf16-MFMA QKV GEMM, BK=64, fully fused epilogue (r15 proven).
// ROUND 18: XCD-CHUNKED grid swizzle (T1).  1D grid of 448 (448%8==0 ->
// bijective): xcd=bid%8 owns m-panels y = xcd*4 + (idx%4), x = idx/14 over
// idx=bid/8.  Old dim3(14,32) round-robined every 512KB A-panel across all
// 8 XCDs (each XCD touched most of the 16.8MB A through L3); now each XCD
// L2 holds 4 A-panels (2MB < 4MB) for its 56 blocks.  Index remap only.
// ---------------------------------------------------------------------------
__global__ __launch_bounds__(256) void gemm_qkv_mfma(
    const ushort_t* __restrict__ xb, const ushort_t* __restrict__ wt,
    ushort_t* __restrict__ qf, ushort_t* __restrict__ kf,
    ushort_t* __restrict__ vf) {
  __shared__ ushort_t At[128 * 64];
  __shared__ ushort_t Bt[128 * 64];
  const int tid = threadIdx.x;
  const int wave = tid >> 6, lane = tid & 63;
  const int quad = lane >> 4, l16 = lane & 15;
  // XCD-chunked decode: 448 blocks = 8 XCDs x (14 n-blocks x 4 m-panels)
  const int xcd = blockIdx.x & 7;
  const int idx = blockIdx.x >> 3;          // 0..55
  const int nb = idx / 4;                   // 0..13
  const int yb = xcd * 4 + (idx & 3);       // 0..31
  const int m0 = yb * 128, n0 = nb * 128;
  const int wm = (wave & 1) * 64, wn = (wave >> 1) * 64;
  const int key = (l16 >> 1) & 3;
  const int ntiles = (n0 >= 1280) ? 16 : 32;

  f32x4 acc[4][4];
#pragma unroll
  for (int i = 0; i < 4; i++)
#pragma unroll
    for (int j = 0; j < 4; j++) acc[i][j] = (f32x4){0.f, 0.f, 0.f, 0.f};

  const int rA = wave * 32 + (lane >> 3);
  const int cA = (lane & 7) * 8;
  const ushort_t* gA = xb + (size_t)(m0 + rA) * KS2 + cA;
  const ushort_t* gB = wt + (size_t)(n0 + rA) * KS2 + cA;

  for (int kt = 0; kt < ntiles; kt++) {
    const int ca = kt * 64;                         // A walks hi then lo
    const int cb = (kt < 16 ? kt : kt - 16) * 64;   // B wraps within hi
    __syncthreads();
#pragma unroll
    for (int j = 0; j < 4; j++) {
      GLD_LDS16(gA + ca + (size_t)(8 * j) * KS2, &At[(wave * 32 + 8 * j) * 64]);
      GLD_LDS16(gB + cb + (size_t)(8 * j) * KS2, &Bt[(wave * 32 + 8 * j) * 64]);
    }
    __syncthreads();

#pragma unroll
    for (int s = 0; s < 2; s++) {
      const int off = s * 32 + ((quad ^ key) * 8);
      short8 af[4], bf[4];
#pragma unroll
      for (int i = 0; i < 4; i++)
        af[i] = *(const short8*)&At[(wm + 16 * i + l16) * 64 + off];
#pragma unroll
      for (int j = 0; j < 4; j++)
        bf[j] = *(const short8*)&Bt[(wn + 16 * j + l16) * 64 + off];
#pragma unroll
      for (int i = 0; i < 4; i++)
#pragma unroll
        for (int j = 0; j < 4; j++)
          acc[i][j] = __builtin_amdgcn_mfma_f32_16x16x32_bf16(
              af[i], bf[j], acc[i][j], 0, 0, 0);
    }
  }

  const int b = m0 >> 11;   // whole block shares one batch (128 | 2048)

  if (n0 >= 1280) {
    // ---- fused vscatter: bf16 cast + PV B-fragment layout store ----
    const int g = (n0 - 1280) >> 7;
    ushort_t* vg = vf + (size_t)(b * 4 + g) * 262144;
#pragma unroll
    for (int i = 0; i < 4; i++) {
      int mbase = m0 + wm + 16 * i + quad * 4;
#pragma unroll
      for (int jn = 0; jn < 4; jn++) {
        int nv = (wn >> 4) + jn;
#pragma unroll
        for (int r = 0; r < 4; r++) {
          int t = (mbase + r) & 2047;
          int tk = t >> 6, ks = (t >> 5) & 1, qd = (t >> 3) & 3, jj = t & 7;
          size_t off = ((size_t)(tk * 16 + ks * 8 + nv) * 4 + qd) * 128 +
                       l16 * 8 + jj;
          vg[off] = f2bf(acc[i][jn][r]);
        }
      }
    }
  } else {
    // ---- fused RoPE + qk-norm + fragment store ----
    const int headn = n0 + wn;            // 64-aligned: one head per wave
    const bool isq = headn < 1024;
    ushort_t* dstbase = isq
        ? qf + (size_t)(b * 16 + (headn >> 6)) * 131072
        : kf + (size_t)(b * 4 + ((headn - 1024) >> 6)) * 131072;
    const float c0 = 0.4152410118074239f;          // log2(10000)/32
    const float inv_lo = exp2f(-(float)l16 * c0);
    const float inv_hi = exp2f(-(float)(16 + l16) * c0);
    const int jj = l16 & 7;

#pragma unroll
    for (int i = 0; i < 4; i++) {
#pragma unroll
      for (int r = 0; r < 4; r++) {
        int t = (m0 + wm + 16 * i + quad * 4 + r) & 2047;
        float sn0, cs0, sn1, cs1;
        __sincosf((float)t * inv_lo, &sn0, &cs0);
        __sincosf((float)t * inv_hi, &sn1, &cs1);
        // d = 16*j + l16; partner d^32 -> register j^2 (same lane)
        float rv0 = acc[i][0][r] * cs0 - acc[i][2][r] * sn0;   // d in [0,16)
        float rv1 = acc[i][1][r] * cs1 - acc[i][3][r] * sn1;   // d in [16,32)
        float rv2 = acc[i][2][r] * cs0 + acc[i][0][r] * sn0;   // d in [32,48)
        float rv3 = acc[i][3][r] * cs1 + acc[i][1][r] * sn1;   // d in [48,64)
        float ss = rv0 * rv0 + rv1 * rv1 + rv2 * rv2 + rv3 * rv3;
        ss += __shfl_xor(ss, 1, 64);
        ss += __shfl_xor(ss, 2, 64);
        ss += __shfl_xor(ss, 4, 64);
        ss += __shfl_xor(ss, 8, 64);
        float sc = 1.0f / (sqrtf(ss) + 1e-6f);
        int kt8 = t >> 6, tt = t & 63;
        int l16v = tt & 15, nt = tt >> 4;
        float rv[4] = {rv0, rv1, rv2, rv3};
#pragma unroll
        for (int j = 0; j < 4; j++) {
          int ks = j >> 1;
          int qd = (2 * j + (l16 >> 3)) & 3;
          size_t idx512 = isq ? (size_t)(kt8 * 8 + nt * 2 + ks)
                              : (size_t)(kt8 * 8 + ks * 4 + nt);
          dstbase[idx512 * 512 + qd * 128 + l16v * 8 + jj] = f2bf(rv[j] * sc);
        }
      }
    }
  }
}

// ---------------------------------------------------------------------------
// Kernel 3: bf16-MFMA causal flash attention (ROUND-15 BODY + decode,
// proven 66.0us).  Single-buffer K/V LDS staging (2 barriers wrap staging
// only), 4 blocks/CU declared, serpentine balanced slot map, v_cvt_pk f2bf
// + fma exp arg.  r17's XCD pin halved FETCH but was duration-neutral ->
// reverted to the measured-best decode; attn is at a structural plateau.
// ---------------------------------------------------------------------------
__global__ __launch_bounds__(256, 4) void attn(
    const ushort_t* __restrict__ qf, const ushort_t* __restrict__ kf,
    const ushort_t* __restrict__ vf, const float* __restrict__ lobo,
    const float* __restrict__ qknf, float* __restrict__ y) {
  const int f = blockIdx.x;            // 1024 blocks
  const int bh = f & 31;
  const int slot = f >> 5;             // 0..31
  int tq;
  if (slot < 8)       tq = 31 - slot;  // 31..24
  else if (slot < 16) tq = 8 + slot;   // 16..23
  else if (slot < 24) tq = 31 - slot;  // 15..8
  else                tq = slot - 24;  // 0..7
  const int b = bh >> 4;
  const int h = bh & 15;
  const int g = h >> 2;

  __shared__ ushort_t KV[12288];       // [K: 8 x 512 | V: 16 x 512] per kt
  __shared__ ushort_t Ps[4 * 1088];    // per-wave 16 rows x 68

  const int tid = threadIdx.x;
  const int wave = tid >> 6, lane = tid & 63;
  const int quad = lane >> 4, l16 = lane & 15;
  ushort_t* PsW = &Ps[wave * 1088];

  short8 bones;
  {
    short bv = (l16 == 0) ? (short)0x3F80 : (short)0;
#pragma unroll
    for (int j = 0; j < 8; j++) bones[j] = bv;
  }

  const ushort_t* qbase = qf + (size_t)(b * 16 + h) * 131072 + lane * 8;
  short8 aq0 = *(const short8*)&qbase[(size_t)(tq * 8 + wave * 2 + 0) * 512];
  short8 aq1 = *(const short8*)&qbase[(size_t)(tq * 8 + wave * 2 + 1) * 512];

  f32x4 o[9];
#pragma unroll
  for (int nv = 0; nv < 9; nv++) o[nv] = (f32x4){0.f, 0.f, 0.f, 0.f};

  const float gsc = qknf[0];
  const float sinkp = __expf(lobo[h] - gsc);

  const int row = tq * 64 + wave * 16 + quad * 4;   // +r

  // per-lane global pointers for staging (lane*8 element offset built in)
  const ushort_t* kgl = kf + (size_t)(b * 4 + g) * 131072 + lane * 8;
  const ushort_t* vgl = vf + (size_t)(b * 4 + g) * 262144 + lane * 8;

  for (int kt = 0; kt <= tq; kt++) {
    // ---- stage K+V tile into LDS (barriers wrap staging ONLY) ----
    __syncthreads();   // previous iteration's KV reads complete
    {
      const ushort_t* gk = kgl + (size_t)kt * 4096;
      const ushort_t* gv = vgl + (size_t)kt * 8192;
      GLD_LDS16(gk + (wave * 2 + 0) * 512, &KV[(wave * 2 + 0) * 512]);
      GLD_LDS16(gk + (wave * 2 + 1) * 512, &KV[(wave * 2 + 1) * 512]);
#pragma unroll
      for (int j = 0; j < 4; j++)
        GLD_LDS16(gv + (wave * 4 + j) * 512, &KV[4096 + (wave * 4 + j) * 512]);
    }
    __syncthreads();   // staging complete (implicit vmcnt drain)

    // ---- QK: K frags from LDS in two batches of 4 ----
    f32x4 s[4];
#pragma unroll
    for (int nt = 0; nt < 4; nt++) s[nt] = (f32x4){0.f, 0.f, 0.f, 0.f};
    {
      short8 kb[4];
#pragma unroll
      for (int u = 0; u < 4; u++)
        kb[u] = *(const short8*)&KV[u * 512 + lane * 8];
      __builtin_amdgcn_s_setprio(1);
#pragma unroll
      for (int nt = 0; nt < 4; nt++)
        s[nt] = __builtin_amdgcn_mfma_f32_16x16x32_bf16(aq0, kb[nt], s[nt], 0, 0, 0);
      __builtin_amdgcn_s_setprio(0);
#pragma unroll
      for (int u = 0; u < 4; u++)
        kb[u] = *(const short8*)&KV[(4 + u) * 512 + lane * 8];
      __builtin_amdgcn_s_setprio(1);
#pragma unroll
      for (int nt = 0; nt < 4; nt++)
        s[nt] = __builtin_amdgcn_mfma_f32_16x16x32_bf16(aq1, kb[nt], s[nt], 0, 0, 0);
      __builtin_amdgcn_s_setprio(0);
    }

    // ---- mask + exp + bf16 store; causal cmp only on diagonal iter ----
    if (kt == tq) {
#pragma unroll
      for (int nt = 0; nt < 4; nt++) {
        int key = kt * 64 + l16 + nt * 16;
#pragma unroll
        for (int r = 0; r < 4; r++) {
          float pv = (key <= row + r) ? __expf(fmaf(s[nt][r], gsc, -gsc)) : 0.f;
          PsW[(quad * 4 + r) * 68 + nt * 16 + l16] = f2bf_hw(pv);
        }
      }
    } else {
#pragma unroll
      for (int nt = 0; nt < 4; nt++)
#pragma unroll
        for (int r = 0; r < 4; r++)
          PsW[(quad * 4 + r) * 68 + nt * 16 + l16] =
              f2bf_hw(__expf(fmaf(s[nt][r], gsc, -gsc)));
    }

    // ---- read P fragments, PV with V frags from LDS (4 batches of 4) ----
    short8 ap0 = *(const short8*)&PsW[l16 * 68 + quad * 8];
    short8 ap1 = *(const short8*)&PsW[l16 * 68 + 32 + quad * 8];
    {
      short8 vb[4];
#pragma unroll
      for (int u = 0; u < 4; u++)
        vb[u] = *(const short8*)&KV[4096 + u * 512 + lane * 8];
      __builtin_amdgcn_s_setprio(1);
#pragma unroll
      for (int nv = 0; nv < 4; nv++)
        o[nv] = __builtin_amdgcn_mfma_f32_16x16x32_bf16(ap0, vb[nv], o[nv], 0, 0, 0);
      __builtin_amdgcn_s_setprio(0);
#pragma unroll
      for (int u = 0; u < 4; u++)
        vb[u] = *(const short8*)&KV[4096 + (4 + u) * 512 + lane * 8];
      __builtin_amdgcn_s_setprio(1);
#pragma unroll
      for (int nv = 0; nv < 4; nv++)
        o[4 + nv] = __builtin_amdgcn_mfma_f32_16x16x32_bf16(ap0, vb[nv], o[4 + nv], 0, 0, 0);
      o[8] = __builtin_amdgcn_mfma_f32_16x16x32_bf16(ap0, bones, o[8], 0, 0, 0);
      o[8] = __builtin_amdgcn_mfma_f32_16x16x32_bf16(ap1, bones, o[8], 0, 0, 0);
      __builtin_amdgcn_s_setprio(0);
#pragma unroll
      for (int u = 0; u < 4; u++)
        vb[u] = *(const short8*)&KV[4096 + (8 + u) * 512 + lane * 8];
      __builtin_amdgcn_s_setprio(1);
#pragma unroll
      for (int nv = 0; nv < 4; nv++)
        o[nv] = __builtin_amdgcn_mfma_f32_16x16x32_bf16(ap1, vb[nv], o[nv], 0, 0, 0);
      __builtin_amdgcn_s_setprio(0);
#pragma unroll
      for (int u = 0; u < 4; u++)
        vb[u] = *(const short8*)&KV[4096 + (12 + u) * 512 + lane * 8];
      __builtin_amdgcn_s_setprio(1);
#pragma unroll
      for (int nv = 0; nv < 4; nv++)
        o[4 + nv] = __builtin_amdgcn_mfma_f32_16x16x32_bf16(ap1, vb[nv], o[4 + nv], 0, 0, 0);
      __builtin_amdgcn_s_setprio(0);
    }
  }

  // epilogue: l = sink + mfma row-sum (col 0 of o[8]); normalize; head-sum
#pragma unroll
  for (int r = 0; r < 4; r++) {
    float lm = __shfl(o[8][r], lane & 48, 64);
    float invl = 1.0f / (lm + sinkp);
    size_t gRow = (size_t)b * T_ + row + r;
#pragma unroll
    for (int nv = 0; nv < 8; nv++)
      atomicAdd(&y[gRow * 128 + nv * 16 + l16], o[nv][r] * invl);
  }
}

// ---------------------------------------------------------------------------
// Kernel 4: out = y[4096][128] @ Wproj[128][1024] via bf16 MFMA.
// ---------------------------------------------------------------------------
__global__ __launch_bounds__(256) void out_proj(
    const float* __restrict__ y, const ushort_t* __restrict__ wpf,
    float* __restrict__ out) {
  __shared__ ushort_t yl[128 * 136];
  const int tid = threadIdx.x;
  const int wave = tid >> 6, lane = tid & 63;
  const int quad = lane >> 4, l16 = lane & 15;
  const int n0 = blockIdx.x * 128, m0 = blockIdx.y * 128;
  const int wm = (wave & 1) * 64, wn = (wave >> 1) * 64;

#pragma unroll
  for (int it = 0; it < 8; it++) {
    int p = it * 256 + tid;
    int row = p >> 4, c8 = p & 15;
    const float* src = &y[(size_t)(m0 + row) * 128 + c8 * 8];
    float4 v0 = *(const float4*)&src[0];
    float4 v1 = *(const float4*)&src[4];
    float fv[8] = {v0.x, v0.y, v0.z, v0.w, v1.x, v1.y, v1.z, v1.w};
    short8 hv;
#pragma unroll
    for (int c = 0; c < 8; c++) hv[c] = (short)f2bf(fv[c]);
    *(short8*)&yl[row * 136 + c8 * 8] = hv;
  }
  __syncthreads();

  f32x4 acc[4][4];
#pragma unroll
  for (int i = 0; i < 4; i++)
#pragma unroll
    for (int j = 0; j < 4; j++) acc[i][j] = (f32x4){0.f, 0.f, 0.f, 0.f};

#pragma unroll
  for (int ks = 0; ks < 4; ks++) {
    short8 af[4], bfr[4];
#pragma unroll
    for (int i = 0; i < 4; i++)
      af[i] = *(const short8*)&yl[(wm + 16 * i + l16) * 136 + (ks * 4 + quad) * 8];
    const ushort_t* wb = wpf + (((size_t)(n0 >> 7) * 4 + ks) * 8) * 512;
#pragma unroll
    for (int j = 0; j < 4; j++)
      bfr[j] = *(const short8*)&wb[((size_t)((wn >> 4) + j)) * 512 + lane * 8];
#pragma unroll
    for (int i = 0; i < 4; i++)
#pragma unroll
      for (int j = 0; j < 4; j++)
        acc[i][j] = __builtin_amdgcn_mfma_f32_16x16x32_bf16(
            af[i], bfr[j], acc[i][j], 0, 0, 0);
  }

#pragma unroll
  for (int i = 0; i < 4; i++) {
    int m = m0 + wm + 16 * i + quad * 4;
#pragma unroll
    for (int j = 0; j < 4; j++) {
      int n = n0 + wn + 16 * j + l16;
#pragma unroll
      for (int r = 0; r < 4; r++)
        out[(size_t)(m + r) * 1024 + n] = acc[i][j][r];
    }
  }
}

// ---------------------------------------------------------------------------
extern "C" void kernel_launch(void* const* d_in, const int* in_sizes, int n_in,
                              void* d_out, int out_size, void* d_ws, size_t ws_size,
                              hipStream_t stream) {
  const float* x     = (const float*)d_in[0];
  const float* Wq    = (const float*)d_in[2];
  const float* Wk    = (const float*)d_in[3];
  const float* Wv    = (const float*)d_in[4];
  const float* Wproj = (const float*)d_in[5];
  const float* lobo  = (const float*)d_in[6];
  const float* qknf  = (const float*)d_in[7];
  float* out = (float*)d_out;

  // ws layout (footprint unchanged; qkv f32 intermediate eliminated):
  //  [0, 8.39MB)    qf bf16 (4,194,304) — written by gemm, read by attn
  //  [8.39, 10.49)  kf bf16 (1,048,576)
  //  [10.49, 14.68) vf bf16 (2,097,152)
  //  [14.68, 16.78) y  f32  (524,288) — zeroed by prep, atomics by attn
  //  [29.36, 46.14) xb bf16 (8,388,608) — written by prep, read by gemm
  //  [46.14, 53.48) wt bf16;  [53.48, 53.74) wpf bf16
  //  All producer->consumer pairs disjoint: no intra-kernel aliases.
  ushort_t* qf = (ushort_t*)d_ws;                                 // 4,194,304
  ushort_t* kf = qf + (size_t)B_ * H_ * T_ * 64;                  // 1,048,576
  ushort_t* vf = kf + (size_t)B_ * G_ * T_ * 64;                  // 2,097,152
  float* y = (float*)(vf + (size_t)B_ * G_ * T_ * 128);           //   524,288 f32
  ushort_t* xb = (ushort_t*)((float*)d_ws + (size_t)B_ * T_ * NQKV);  // 8,388,608
  ushort_t* wt = xb + (size_t)B_ * T_ * KS2;                      // 3,670,016
  ushort_t* wpf = wt + (size_t)NQKV * KS2;                        //   131,072

  // 4 dispatches: prep(+y-zero) -> gemm(+rope+vscatter) -> attn -> out_proj
  prep<<<3072, 256, 0, stream>>>(x, Wq, Wk, Wv, Wproj, xb, wt, wpf, y);

  gemm_qkv_mfma<<<448, 256, 0, stream>>>(xb, wt, qf, kf, vf);

  attn<<<B_ * H_ * 32, 256, 0, stream>>>(qf, kf, vf, lobo, qknf, y);

  dim3 go(8, 32);
  out_proj<<<go, 256, 0, stream>>>(y, wpf, out);
}